// Round 1
// baseline (297.459 us; speedup 1.0000x reference)
//
#include <hip/hip_runtime.h>
#include <stdint.h>

// IDCT (DCT-III, DREAMPlace scaling) as bf16 MFMA GEMM:
//   out[m][p] = sum_n x[m][n] * Bt[p][n],
//   Bt[p][0] = 1, Bt[p][n] = 2*cos(pi*n*(2p+1)/(2N)), N = 4096.
// ws layout: [0, 32MB) = x in bf16, [32MB, 64MB) = Bt in bf16.

#define Md 4096
#define Nd 4096
#define Kd 4096
#define BM 128
#define BN 128
#define BK 32

typedef short bf16x8 __attribute__((ext_vector_type(8)));
typedef float floatx4 __attribute__((ext_vector_type(4)));
typedef unsigned short ushort_t;

__device__ __forceinline__ ushort_t f2bf(float f) {
  union { float f; uint32_t u; } v; v.f = f;
  uint32_t u = v.u;
  // round-to-nearest-even bf16 truncation (inputs are finite normals)
  return (ushort_t)((u + 0x7fffu + ((u >> 16) & 1u)) >> 16);
}

// x fp32 -> bf16, 8 elems/thread (16B load x2, 16B store)
__global__ __launch_bounds__(256) void cvt_kernel(const float* __restrict__ x,
                                                  ushort_t* __restrict__ o) {
  int i = (blockIdx.x * 256 + threadIdx.x) * 8;
  float4 a = *(const float4*)(x + i);
  float4 b = *(const float4*)(x + i + 4);
  union { ushort_t us[8]; int4 v; } pk;
  pk.us[0] = f2bf(a.x); pk.us[1] = f2bf(a.y);
  pk.us[2] = f2bf(a.z); pk.us[3] = f2bf(a.w);
  pk.us[4] = f2bf(b.x); pk.us[5] = f2bf(b.y);
  pk.us[6] = f2bf(b.z); pk.us[7] = f2bf(b.w);
  *(int4*)(o + i) = pk.v;
}

// Bt[p][n] coefficients, 8 elems/thread. Integer mod-16384 range reduction
// keeps the cos argument < 2*pi (exact in fp32); n*(2p+1) < 2^31 fits int32.
__global__ __launch_bounds__(256) void fill_kernel(ushort_t* __restrict__ Bt) {
  int idx = (blockIdx.x * 256 + threadIdx.x) * 8;
  int p = idx >> 12;       // row = output frequency index
  int n0 = idx & 4095;     // col = reduction index
  int tp = 2 * p + 1;
  const float s = 3.14159265358979f / 8192.0f;  // pi/(2N)
  union { ushort_t us[8]; int4 v; } pk;
#pragma unroll
  for (int j = 0; j < 8; ++j) {
    int n = n0 + j;                    // row len 4096 divisible by 8 -> same p
    int t = (n * tp) & 16383;          // mod 4N (cos period in t)
    float c = (n == 0) ? 1.0f : 2.0f * __cosf(s * (float)t);
    pk.us[j] = f2bf(c);
  }
  *(int4*)(Bt + idx) = pk.v;
}

// m97-structure GEMM: C[MdxNd] fp32 = A[Md x Kd](bf16) * Bt[Nd x Kd]^T(bf16)
// 128x128 tile, BK=32, 256 threads (4 waves, 2x2), 4x4 16x16x32 frags/wave.
__global__ __launch_bounds__(256) void gemm_bt(const ushort_t* __restrict__ A,
                                               const ushort_t* __restrict__ B,
                                               float* __restrict__ C) {
  // LDS layout is linear tile order (row-major, row stride 64B) — REQUIRED by
  // global_load_lds (wave-uniform base + lane*16), so no padding possible.
  __shared__ __align__(16) ushort_t As[BM * BK];
  __shared__ __align__(16) ushort_t Bs[BN * BK];

  const int tid = threadIdx.x;
  const int wid = tid >> 6;
  const int lane = tid & 63;

  const int bm = blockIdx.y * BM;
  const int bn = blockIdx.x * BN;

  const int wm = (wid & 1) * 64;   // wave's 64x64 quadrant
  const int wn = (wid >> 1) * 64;

  const int lrow = lane & 15;        // fragment row within 16
  const int kq = (lane >> 4) * 8;    // k offset per lane quad

  floatx4 acc[4][4] = {};

  const ushort_t* Abase = A + bm * Kd;
  const ushort_t* Bbase = B + bn * Kd;

  // Staging: tile = 128 rows x 64B = 8192B; 256 thr x 16B = 4096B -> 2 issues.
  // chunk c = issue*256 + tid; row = c>>2; elem-in-row = (c&3)*8.
  const int c0 = tid;
  const int c1 = 256 + tid;
  const int r0 = c0 >> 2, e0 = (c0 & 3) * 8;
  const int r1 = c1 >> 2, e1 = (c1 & 3) * 8;
  // wave-uniform LDS bases (elements); HW scatters lane*16B from here
  const int l0 = (wid * 64) * 8;
  const int l1 = (256 + wid * 64) * 8;

  for (int k0 = 0; k0 < Kd; k0 += BK) {
    __builtin_amdgcn_global_load_lds(
        (const __attribute__((address_space(1))) void*)(Abase + r0 * Kd + k0 + e0),
        (__attribute__((address_space(3))) void*)(As + l0), 16, 0, 0);
    __builtin_amdgcn_global_load_lds(
        (const __attribute__((address_space(1))) void*)(Abase + r1 * Kd + k0 + e1),
        (__attribute__((address_space(3))) void*)(As + l1), 16, 0, 0);
    __builtin_amdgcn_global_load_lds(
        (const __attribute__((address_space(1))) void*)(Bbase + r0 * Kd + k0 + e0),
        (__attribute__((address_space(3))) void*)(Bs + l0), 16, 0, 0);
    __builtin_amdgcn_global_load_lds(
        (const __attribute__((address_space(1))) void*)(Bbase + r1 * Kd + k0 + e1),
        (__attribute__((address_space(3))) void*)(Bs + l1), 16, 0, 0);
    __syncthreads();  // drains vmcnt -> staging visible

    bf16x8 af[4], bfr[4];
#pragma unroll
    for (int f = 0; f < 4; ++f) {
      af[f]  = *(const bf16x8*)(As + (wm + f * 16 + lrow) * BK + kq);
      bfr[f] = *(const bf16x8*)(Bs + (wn + f * 16 + lrow) * BK + kq);
    }
#pragma unroll
    for (int im = 0; im < 4; ++im)
#pragma unroll
      for (int jn = 0; jn < 4; ++jn)
        acc[im][jn] = __builtin_amdgcn_mfma_f32_16x16x32_bf16(
            af[im], bfr[jn], acc[im][jn], 0, 0, 0);
    __syncthreads();  // all waves done reading before next overwrite
  }

  // Epilogue: verified C/D mapping col=lane&15, row=(lane>>4)*4+r
#pragma unroll
  for (int im = 0; im < 4; ++im) {
    int rb = bm + wm + im * 16 + (lane >> 4) * 4;
#pragma unroll
    for (int jn = 0; jn < 4; ++jn) {
      int col = bn + wn + jn * 16 + lrow;
      float* cp = C + (size_t)rb * Nd + col;
#pragma unroll
      for (int r = 0; r < 4; ++r)
        cp[(size_t)r * Nd] = acc[im][jn][r];
    }
  }
}

extern "C" void kernel_launch(void* const* d_in, const int* in_sizes, int n_in,
                              void* d_out, int out_size, void* d_ws, size_t ws_size,
                              hipStream_t stream) {
  const float* x = (const float*)d_in[0];
  float* out = (float*)d_out;
  ushort_t* Axb = (ushort_t*)d_ws;                 // 4096*4096 bf16 = 32 MB
  ushort_t* Btw = Axb + (size_t)Md * Kd;           // next 32 MB

  // 16.7M elems / (8 per thread * 256) = 8192 blocks
  cvt_kernel<<<8192, 256, 0, stream>>>(x, Axb);
  fill_kernel<<<8192, 256, 0, stream>>>(Btw);

  dim3 grid(Nd / BN, Md / BM);  // 32 x 32
  gemm_bt<<<grid, 256, 0, stream>>>(Axb, Btw, out);
}

// Round 2
// 233.594 us; speedup vs baseline: 1.2734x; 1.2734x over previous
//
#include <hip/hip_runtime.h>
#include <stdint.h>

// IDCT (DCT-III, DREAMPlace scaling) via even/odd split:
//   E[m][p] = sum_{n even} x[m][n]*c(n,p),  O[m][p] = sum_{n odd} ...,
//   out[p] = E+O, out[N-1-p] = E-O   (c(n,N-1-p) = (-1)^n c(n,p)).
// Two M x 2048 x 2048 bf16 GEMMs = half the MACs of the direct form.
// ws: [0,32MB) A' bf16 (even cols then odd cols), [32,40) Ce, [40,48) Co.

#define Md 4096
#define Nfull 4096
#define Ph 2048   // half output width
#define Kh 2048   // half reduction
#define BM 128
#define BN 128
#define BK 32

typedef short bf16x8 __attribute__((ext_vector_type(8)));
typedef float floatx4 __attribute__((ext_vector_type(4)));
typedef unsigned short ushort_t;

__device__ __forceinline__ ushort_t f2bf(float f) {
  union { float f; uint32_t u; } v; v.f = f;
  uint32_t u = v.u;
  return (ushort_t)((u + 0x7fffu + ((u >> 16) & 1u)) >> 16);
}

// x fp32 -> bf16 with even/odd column deinterleave.
// Thread handles 8 consecutive floats of one row: 4 -> even half, 4 -> odd.
__global__ __launch_bounds__(256) void cvt_kernel(const float* __restrict__ x,
                                                  ushort_t* __restrict__ o) {
  int i = (blockIdx.x * 256 + threadIdx.x) * 8;
  int m = i >> 12;          // row
  int j = i & 4095;         // col within row (multiple of 8)
  float4 a = *(const float4*)(x + i);
  float4 b = *(const float4*)(x + i + 4);
  union { ushort_t us[4]; int2 v; } ev, od;
  ev.us[0] = f2bf(a.x); od.us[0] = f2bf(a.y);
  ev.us[1] = f2bf(a.z); od.us[1] = f2bf(a.w);
  ev.us[2] = f2bf(b.x); od.us[2] = f2bf(b.y);
  ev.us[3] = f2bf(b.z); od.us[3] = f2bf(b.w);
  int half = j >> 1;        // 4-aligned
  *(int2*)(o + m * Nfull + half) = ev.v;
  *(int2*)(o + m * Nfull + Ph + half) = od.v;
}

// Ce[p][ne] = c(2ne, p)  (ne=0 -> 1.0), Co[p][no] = c(2no+1, p), p in [0,2048).
// c(n,p) = 2*cos(pi*n*(2p+1)/8192) for n>0. Integer mod-16384 reduction.
__global__ __launch_bounds__(256) void fill_kernel(ushort_t* __restrict__ Ce,
                                                   ushort_t* __restrict__ Co) {
  int idx = (blockIdx.x * 256 + threadIdx.x) * 8;   // [0, 8M)
  const float s = 3.14159265358979f / 8192.0f;      // pi/(2N)
  union { ushort_t us[8]; int4 v; } pk;
  if (idx < Ph * Kh) {                 // Ce
    int p = idx >> 11;
    int ne0 = idx & 2047;
    int tp = 2 * p + 1;
#pragma unroll
    for (int jj = 0; jj < 8; ++jj) {
      int n = 2 * (ne0 + jj);
      int t = (n * tp) & 16383;
      float c = (n == 0) ? 1.0f : 2.0f * __cosf(s * (float)t);
      pk.us[jj] = f2bf(c);
    }
    *(int4*)(Ce + idx) = pk.v;
  } else {                             // Co
    int local = idx - Ph * Kh;
    int p = local >> 11;
    int no0 = local & 2047;
    int tp = 2 * p + 1;
#pragma unroll
    for (int jj = 0; jj < 8; ++jj) {
      int n = 2 * (no0 + jj) + 1;
      int t = (n * tp) & 16383;
      pk.us[jj] = f2bf(2.0f * __cosf(s * (float)t));
    }
    *(int4*)(Co + local) = pk.v;
  }
}

// m97-structure GEMM, z in {0,1} selects (A even half, Ce) -> E or (odd, Co) -> O.
// E written to C[:, 0:2048], O to C[:, 2048:4096] (fp32, row stride 4096).
__global__ __launch_bounds__(256) void gemm_bt(const ushort_t* __restrict__ A,
                                               const ushort_t* __restrict__ Ce,
                                               const ushort_t* __restrict__ Co,
                                               float* __restrict__ C) {
  __shared__ __align__(16) ushort_t As[BM * BK];
  __shared__ __align__(16) ushort_t Bs[BN * BK];

  const int tid = threadIdx.x;
  const int wid = tid >> 6;
  const int lane = tid & 63;
  const int z = blockIdx.z;

  const int bm = blockIdx.y * BM;
  const int bn = blockIdx.x * BN;

  const int wm = (wid & 1) * 64;
  const int wn = (wid >> 1) * 64;

  const int lrow = lane & 15;
  const int kq = (lane >> 4) * 8;

  floatx4 acc[4][4] = {};

  // A row stride is Nfull (deinterleaved halves side by side)
  const ushort_t* Abase = A + (size_t)bm * Nfull + z * Kh;
  const ushort_t* Bsel = z ? Co : Ce;
  const ushort_t* Bbase = Bsel + (size_t)bn * Kh;   // row stride Kh

  // staging: 128 rows x 64B per tile; 256 thr x 16B -> 2 issues per tile
  const int r0 = tid >> 2, e0 = (tid & 3) * 8;
  const int r1 = (256 + tid) >> 2, e1 = (tid & 3) * 8;  // (256+tid)&3 == tid&3
  const int l0 = (wid * 64) * 8;
  const int l1 = (256 + wid * 64) * 8;

  for (int k0 = 0; k0 < Kh; k0 += BK) {
    __builtin_amdgcn_global_load_lds(
        (const __attribute__((address_space(1))) void*)(Abase + (size_t)r0 * Nfull + k0 + e0),
        (__attribute__((address_space(3))) void*)(As + l0), 16, 0, 0);
    __builtin_amdgcn_global_load_lds(
        (const __attribute__((address_space(1))) void*)(Abase + (size_t)r1 * Nfull + k0 + e1),
        (__attribute__((address_space(3))) void*)(As + l1), 16, 0, 0);
    __builtin_amdgcn_global_load_lds(
        (const __attribute__((address_space(1))) void*)(Bbase + (size_t)r0 * Kh + k0 + e0),
        (__attribute__((address_space(3))) void*)(Bs + l0), 16, 0, 0);
    __builtin_amdgcn_global_load_lds(
        (const __attribute__((address_space(1))) void*)(Bbase + (size_t)r1 * Kh + k0 + e1),
        (__attribute__((address_space(3))) void*)(Bs + l1), 16, 0, 0);
    __syncthreads();

    bf16x8 af[4], bfr[4];
#pragma unroll
    for (int f = 0; f < 4; ++f) {
      af[f]  = *(const bf16x8*)(As + (wm + f * 16 + lrow) * BK + kq);
      bfr[f] = *(const bf16x8*)(Bs + (wn + f * 16 + lrow) * BK + kq);
    }
#pragma unroll
    for (int im = 0; im < 4; ++im)
#pragma unroll
      for (int jn = 0; jn < 4; ++jn)
        acc[im][jn] = __builtin_amdgcn_mfma_f32_16x16x32_bf16(
            af[im], bfr[jn], acc[im][jn], 0, 0, 0);
    __syncthreads();
  }

  // C/D mapping: col=lane&15, row=(lane>>4)*4+r
  const int cbase = z * Ph + bn + wn;
#pragma unroll
  for (int im = 0; im < 4; ++im) {
    int rb = bm + wm + im * 16 + (lane >> 4) * 4;
#pragma unroll
    for (int jn = 0; jn < 4; ++jn) {
      int col = cbase + jn * 16 + lrow;
      float* cp = C + (size_t)rb * Nfull + col;
#pragma unroll
      for (int r = 0; r < 4; ++r)
        cp[(size_t)r * Nfull] = acc[im][jn][r];
    }
  }
}

// In-place butterfly on C: holds [E | O]; produce
//   out[p] = E[p]+O[p], out[4095-p] = E[p]-O[p]  (p in [0,2048)).
// Thread owns disjoint quartets {p..p+3, 2044-p..2047-p, 2048+p.., 4092-p..}.
__global__ __launch_bounds__(256) void butterfly_kernel(float* __restrict__ C) {
  int m = blockIdx.x;
  int p = threadIdx.x * 4;              // [0, 1024)
  float* row = C + (size_t)m * Nfull;
  float4 e_lo = *(float4*)(row + p);            // E[p+j]
  float4 e_hi = *(float4*)(row + 2044 - p);     // E[2044-p+jj]
  float4 o_lo = *(float4*)(row + 2048 + p);     // O[p+j]
  float4 o_hi = *(float4*)(row + 4092 - p);     // O[2044-p+jj]

  float4 w0, w1, w2, w3;
  // out[p+j] = E+O
  w0.x = e_lo.x + o_lo.x; w0.y = e_lo.y + o_lo.y;
  w0.z = e_lo.z + o_lo.z; w0.w = e_lo.w + o_lo.w;
  // out[2044-p+jj] = E[q]+O[q] elementwise
  w1.x = e_hi.x + o_hi.x; w1.y = e_hi.y + o_hi.y;
  w1.z = e_hi.z + o_hi.z; w1.w = e_hi.w + o_hi.w;
  // out[2048+p+j] = E[2047-p-j] - O[2047-p-j]  -> reversed(e_hi - o_hi)
  w2.x = e_hi.w - o_hi.w; w2.y = e_hi.z - o_hi.z;
  w2.z = e_hi.y - o_hi.y; w2.w = e_hi.x - o_hi.x;
  // out[4092-p+jj] = E[p+3-jj] - O[p+3-jj]     -> reversed(e_lo - o_lo)
  w3.x = e_lo.w - o_lo.w; w3.y = e_lo.z - o_lo.z;
  w3.z = e_lo.y - o_lo.y; w3.w = e_lo.x - o_lo.x;

  *(float4*)(row + p) = w0;
  *(float4*)(row + 2044 - p) = w1;
  *(float4*)(row + 2048 + p) = w2;
  *(float4*)(row + 4092 - p) = w3;
}

extern "C" void kernel_launch(void* const* d_in, const int* in_sizes, int n_in,
                              void* d_out, int out_size, void* d_ws, size_t ws_size,
                              hipStream_t stream) {
  const float* x = (const float*)d_in[0];
  float* out = (float*)d_out;
  ushort_t* Axb = (ushort_t*)d_ws;                     // 32 MB
  ushort_t* Ce = Axb + (size_t)Md * Nfull;             // 8 MB
  ushort_t* Co = Ce + (size_t)Ph * Kh;                 // 8 MB

  cvt_kernel<<<8192, 256, 0, stream>>>(x, Axb);
  fill_kernel<<<4096, 256, 0, stream>>>(Ce, Co);

  dim3 grid(Ph / BN, Md / BM, 2);   // 16 x 32 x 2
  gemm_bt<<<grid, 256, 0, stream>>>(Axb, Ce, Co, out);

  butterfly_kernel<<<Md, 256, 0, stream>>>(out);
}

// Round 3
// 199.005 us; speedup vs baseline: 1.4947x; 1.1738x over previous
//
#include <hip/hip_runtime.h>
#include <stdint.h>

// IDCT (DCT-III, DREAMPlace scaling) via even/odd split, fully fused:
//   E[m][p] = sum_{n even} x[m][n]*c(n,p),  O[m][p] = sum_{n odd} ...,
//   out[p] = E+O, out[N-1-p] = E-O   (c(n,N-1-p) = (-1)^n c(n,p)).
// One prep kernel (cvt + coefficient fill), one fused GEMM that computes
// E and O per tile (dual accumulators) and applies the butterfly in the
// epilogue. 2 launches total (~20us fixed cost per launch observed).
// ws: [0,32MB) A' bf16 (even cols | odd cols), [32,40) Ce, [40,48) Co.

#define Md 4096
#define Nfull 4096
#define Ph 2048   // half output width
#define Kh 2048   // half reduction
#define BM 128
#define BN 128
#define BK 32

typedef short bf16x8 __attribute__((ext_vector_type(8)));
typedef float floatx4 __attribute__((ext_vector_type(4)));
typedef unsigned short ushort_t;

__device__ __forceinline__ ushort_t f2bf(float f) {
  union { float f; uint32_t u; } v; v.f = f;
  uint32_t u = v.u;
  return (ushort_t)((u + 0x7fffu + ((u >> 16) & 1u)) >> 16);
}

// blocks [0,8192): x fp32 -> bf16 even/odd column deinterleave.
// blocks [8192,12288): fill Ce[p][ne]=c(2ne,p), Co[p][no]=c(2no+1,p).
__global__ __launch_bounds__(256) void prep_kernel(const float* __restrict__ x,
                                                   ushort_t* __restrict__ A,
                                                   ushort_t* __restrict__ Ce,
                                                   ushort_t* __restrict__ Co) {
  int b = blockIdx.x;
  if (b < 8192) {
    int i = (b * 256 + threadIdx.x) * 8;
    int m = i >> 12;
    int j = i & 4095;
    float4 a = *(const float4*)(x + i);
    float4 c = *(const float4*)(x + i + 4);
    union { ushort_t us[4]; int2 v; } ev, od;
    ev.us[0] = f2bf(a.x); od.us[0] = f2bf(a.y);
    ev.us[1] = f2bf(a.z); od.us[1] = f2bf(a.w);
    ev.us[2] = f2bf(c.x); od.us[2] = f2bf(c.y);
    ev.us[3] = f2bf(c.z); od.us[3] = f2bf(c.w);
    int half = j >> 1;
    *(int2*)(A + m * Nfull + half) = ev.v;
    *(int2*)(A + m * Nfull + Ph + half) = od.v;
  } else {
    int idx = ((b - 8192) * 256 + threadIdx.x) * 8;  // [0, 8M)
    const float s = 3.14159265358979f / 8192.0f;     // pi/(2N)
    union { ushort_t us[8]; int4 v; } pk;
    if (idx < Ph * Kh) {               // Ce
      int p = idx >> 11;
      int ne0 = idx & 2047;
      int tp = 2 * p + 1;
#pragma unroll
      for (int jj = 0; jj < 8; ++jj) {
        int n = 2 * (ne0 + jj);
        int t = (n * tp) & 16383;      // mod 4N: exact int reduction
        float c = (n == 0) ? 1.0f : 2.0f * __cosf(s * (float)t);
        pk.us[jj] = f2bf(c);
      }
      *(int4*)(Ce + idx) = pk.v;
    } else {                           // Co
      int local = idx - Ph * Kh;
      int p = local >> 11;
      int no0 = local & 2047;
      int tp = 2 * p + 1;
#pragma unroll
      for (int jj = 0; jj < 8; ++jj) {
        int n = 2 * (no0 + jj) + 1;
        int t = (n * tp) & 16383;
        pk.us[jj] = f2bf(2.0f * __cosf(s * (float)t));
      }
      *(int4*)(Co + local) = pk.v;
    }
  }
}

// Fused dual GEMM + butterfly. Block tile: 128 rows (m) x 128 cols (p).
// Computes E and O tiles with separate accumulator sets over K=2048
// (128 K-iters, 32 MFMAs/wave/iter), then writes out[p]=E+O and
// out[4095-p]=E-O. __launch_bounds__(256,2): 2 waves/SIMD -> 256 VGPR/wave
// budget for the 32 floatx4 accumulators + frags without spill.
__global__ __launch_bounds__(256, 2) void gemm_fused(const ushort_t* __restrict__ A,
                                                     const ushort_t* __restrict__ Ce,
                                                     const ushort_t* __restrict__ Co,
                                                     float* __restrict__ out) {
  // Linear tile order (row-major, 64B rows) — REQUIRED by global_load_lds
  // (wave-uniform base + lane*16B), so no bank-conflict padding possible.
  __shared__ __align__(16) ushort_t AsE[BM * BK];
  __shared__ __align__(16) ushort_t AsO[BM * BK];
  __shared__ __align__(16) ushort_t BsE[BN * BK];
  __shared__ __align__(16) ushort_t BsO[BN * BK];

  const int tid = threadIdx.x;
  const int wid = tid >> 6;
  const int lane = tid & 63;

  const int bm = blockIdx.y * BM;
  const int bn = blockIdx.x * BN;

  const int wm = (wid & 1) * 64;
  const int wn = (wid >> 1) * 64;

  const int lrow = lane & 15;
  const int kq = (lane >> 4) * 8;

  floatx4 accE[4][4] = {};
  floatx4 accO[4][4] = {};

  // staging: tile = 128 rows x 64B = 8KB; 256 thr x 16B = 4KB -> 2 issues.
  // chunk c = issue*256+tid: row=c>>2, elem=(c&3)*8; LDS elem offset = 8c.
  const int r0 = tid >> 2, e0 = (tid & 3) * 8;
  const int r1 = r0 + 64;              // (256+tid)>>2 ; (256+tid)&3 == tid&3
  const int l0 = wid * 512;            // wave-uniform LDS base (elements)
  const int l1 = 2048 + wid * 512;

  const ushort_t* Ae = A + (size_t)bm * Nfull;        // even half, row stride 4096
  const ushort_t* Ao = Ae + Ph;                       // odd half
  const ushort_t* Be = Ce + (size_t)bn * Kh;          // row stride 2048
  const ushort_t* Bo = Co + (size_t)bn * Kh;

#define GLDS(src, dst) __builtin_amdgcn_global_load_lds( \
      (const __attribute__((address_space(1))) void*)(src), \
      (__attribute__((address_space(3))) void*)(dst), 16, 0, 0)

  for (int k0 = 0; k0 < Kh; k0 += BK) {
    GLDS(Ae + (size_t)r0 * Nfull + k0 + e0, AsE + l0);
    GLDS(Ae + (size_t)r1 * Nfull + k0 + e0, AsE + l1);
    GLDS(Ao + (size_t)r0 * Nfull + k0 + e0, AsO + l0);
    GLDS(Ao + (size_t)r1 * Nfull + k0 + e0, AsO + l1);
    GLDS(Be + (size_t)r0 * Kh + k0 + e0, BsE + l0);
    GLDS(Be + (size_t)r1 * Kh + k0 + e0, BsE + l1);
    GLDS(Bo + (size_t)r0 * Kh + k0 + e0, BsO + l0);
    GLDS(Bo + (size_t)r1 * Kh + k0 + e0, BsO + l1);
    __syncthreads();   // drains vmcnt -> staging visible

    bf16x8 bE[4], bO[4];
#pragma unroll
    for (int f = 0; f < 4; ++f) {
      bE[f] = *(const bf16x8*)(BsE + (wn + f * 16 + lrow) * BK + kq);
      bO[f] = *(const bf16x8*)(BsO + (wn + f * 16 + lrow) * BK + kq);
    }
#pragma unroll
    for (int im = 0; im < 4; ++im) {
      bf16x8 aE = *(const bf16x8*)(AsE + (wm + im * 16 + lrow) * BK + kq);
      bf16x8 aO = *(const bf16x8*)(AsO + (wm + im * 16 + lrow) * BK + kq);
#pragma unroll
      for (int jn = 0; jn < 4; ++jn) {
        accE[im][jn] = __builtin_amdgcn_mfma_f32_16x16x32_bf16(aE, bE[jn], accE[im][jn], 0, 0, 0);
        accO[im][jn] = __builtin_amdgcn_mfma_f32_16x16x32_bf16(aO, bO[jn], accO[im][jn], 0, 0, 0);
      }
    }
    __syncthreads();   // all waves done reading before next overwrite
  }
#undef GLDS

  // Epilogue butterfly. C/D mapping: col=lane&15, row=(lane>>4)*4+r.
#pragma unroll
  for (int im = 0; im < 4; ++im) {
    int rb = bm + wm + im * 16 + (lane >> 4) * 4;
#pragma unroll
    for (int jn = 0; jn < 4; ++jn) {
      int p = bn + wn + jn * 16 + lrow;
      float* lo = out + (size_t)rb * Nfull + p;
      float* hi = out + (size_t)rb * Nfull + (Nfull - 1 - p);
#pragma unroll
      for (int r = 0; r < 4; ++r) {
        float e = accE[im][jn][r];
        float o = accO[im][jn][r];
        lo[(size_t)r * Nfull] = e + o;
        hi[(size_t)r * Nfull] = e - o;
      }
    }
  }
}

extern "C" void kernel_launch(void* const* d_in, const int* in_sizes, int n_in,
                              void* d_out, int out_size, void* d_ws, size_t ws_size,
                              hipStream_t stream) {
  const float* x = (const float*)d_in[0];
  float* out = (float*)d_out;
  ushort_t* Axb = (ushort_t*)d_ws;                     // 32 MB
  ushort_t* Ce = Axb + (size_t)Md * Nfull;             // 8 MB
  ushort_t* Co = Ce + (size_t)Ph * Kh;                 // 8 MB

  prep_kernel<<<12288, 256, 0, stream>>>(x, Axb, Ce, Co);

  dim3 grid(Ph / BN, Md / BM);  // 16 x 32 = 512 blocks = 2/CU
  gemm_fused<<<grid, 256, 0, stream>>>(Axb, Ce, Co, out);
}